// Round 7
// baseline (127.370 us; speedup 1.0000x reference)
//
#include <hip/hip_runtime.h>

#define BB 32
#define HH 256
#define WW 256
#define CC 4
#define KH 5
#define KW 5
#define FF 8
#define HO (HH - KH + 1)   // 252
#define WO (WW - KW + 1)   // 252
#define PX 2               // output pixels per thread along x; WO % PX == 0
#define NXT (WO / PX)      // 126
#define NCOL (PX + KW - 1) // 6 input columns per thread
#define NTAP (KH * KW)     // 25

typedef _Float16 h2      __attribute__((ext_vector_type(2)));
typedef __fp16   fp16x2  __attribute__((ext_vector_type(2)));
typedef unsigned int u32x4 __attribute__((ext_vector_type(4)));

static __device__ __forceinline__ h2 pkrtz(float a, float b) {
    fp16x2 r = __builtin_amdgcn_cvt_pkrtz(a, b);
    return __builtin_bit_cast(h2, r);
}
static __device__ __forceinline__ h2 ash2(unsigned int u) {
    return __builtin_bit_cast(h2, u);
}

// Fused kernel: per-block weight pack into LDS, then pk-f16 erosion with an
// explicit tap-level double-buffered weight pipeline.
// LDS dword i = tap*16 + f*2 + pair : pk(k[tap, 2*pair, f], k[tap, 2*pair+1, f])
__global__ __launch_bounds__(256) void erosion2d_f16(
    const float* __restrict__ x,
    const float* __restrict__ k,
    float* __restrict__ out)
{
    __shared__ u32x4 lw[NTAP * 4];   // 400 dwords = 1.6 KB, b128-aligned
    unsigned int* lws = reinterpret_cast<unsigned int*>(lw);

    for (int i = threadIdx.x; i < NTAP * 16; i += 256) {
        int t = i >> 4;          // tap
        int rr = i & 15;
        int f = rr >> 1;
        int p = rr & 1;          // channel pair
        float a = k[(t * CC + 2 * p + 0) * FF + f];
        float b = k[(t * CC + 2 * p + 1) * FF + f];
        lws[i] = __builtin_bit_cast(unsigned int, pkrtz(a, b));
    }
    __syncthreads();

    // Grid is exact: 3969 * 256 == 32 * 252 * 126 — no bounds check needed.
    int tid = blockIdx.x * blockDim.x + threadIdx.x;

    int b   = tid / (HO * NXT);
    int rem = tid - b * (HO * NXT);
    int y   = rem / NXT;
    int xt  = rem - y * NXT;
    const int x0 = xt * PX;

    const float* xb = x + (((size_t)b * HH + y) * WW + x0) * CC;

    h2 acc[PX][FF];
    float4 raw[NCOL];
    h2 cur[NCOL][2];

    // Weight double-buffer: tap t computes from w[t&1] while tap t+1
    // prefetches into w[(t+1)&1]. All indices compile-time constant.
    u32x4 w[2][4];
#pragma unroll
    for (int q = 0; q < 4; ++q) w[0][q] = lw[q];      // prefetch tap 0

    // Row 0 loads in flight.
#pragma unroll
    for (int j = 0; j < NCOL; ++j)
        raw[j] = *reinterpret_cast<const float4*>(xb + j * CC);

#pragma unroll
    for (int r = 0; r < KH; ++r) {
        // Convert the row whose loads we just waited on.
#pragma unroll
        for (int j = 0; j < NCOL; ++j) {
            cur[j][0] = pkrtz(raw[j].x, raw[j].y);
            cur[j][1] = pkrtz(raw[j].z, raw[j].w);
        }
        // Issue next row's loads; consumed only after this row's 320 VALU ops.
        if (r + 1 < KH) {
#pragma unroll
            for (int j = 0; j < NCOL; ++j)
                raw[j] = *reinterpret_cast<const float4*>(xb + ((r + 1) * WW + j) * CC);
        }
#pragma unroll
        for (int dx = 0; dx < KW; ++dx) {
            const int tap = r * KW + dx;
            const int cb  = tap & 1;
            // Prefetch next tap's weights (4x ds_read_b128) BEFORE this
            // tap's compute — one full compute block of latency distance.
            if (tap + 1 < NTAP) {
#pragma unroll
                for (int q = 0; q < 4; ++q)
                    w[cb ^ 1][q] = lw[(tap + 1) * 4 + q];
            }
            const u32x4 q0 = w[cb][0], q1 = w[cb][1], q2 = w[cb][2], q3 = w[cb][3];
            h2 w01[FF], w23[FF];
            w01[0] = ash2(q0[0]); w23[0] = ash2(q0[1]);
            w01[1] = ash2(q0[2]); w23[1] = ash2(q0[3]);
            w01[2] = ash2(q1[0]); w23[2] = ash2(q1[1]);
            w01[3] = ash2(q1[2]); w23[3] = ash2(q1[3]);
            w01[4] = ash2(q2[0]); w23[4] = ash2(q2[1]);
            w01[5] = ash2(q2[2]); w23[5] = ash2(q2[3]);
            w01[6] = ash2(q3[0]); w23[6] = ash2(q3[1]);
            w01[7] = ash2(q3[2]); w23[7] = ash2(q3[3]);
#pragma unroll
            for (int p = 0; p < PX; ++p) {
                const h2 c01 = cur[dx + p][0];
                const h2 c23 = cur[dx + p][1];
#pragma unroll
                for (int f = 0; f < FF; ++f) {
                    h2 d01 = c01 - w01[f];
                    h2 d23 = c23 - w23[f];
                    h2 m   = __builtin_elementwise_min(d01, d23);
                    if (tap == 0)
                        acc[p][f] = m;                 // init from first tap
                    else
                        acc[p][f] = __builtin_elementwise_min(acc[p][f], m);
                }
            }
        }
    }

    // Epilogue: horizontal min over the channel pair, f16->f32, 64 B/thread.
#pragma unroll
    for (int p = 0; p < PX; ++p) {
        float rr[FF];
#pragma unroll
        for (int f = 0; f < FF; ++f) {
            _Float16 m = __builtin_elementwise_min(acc[p][f][0], acc[p][f][1]);
            rr[f] = (float)m;
        }
        float* op = out + ((size_t)tid * PX + p) * FF;
        *reinterpret_cast<float4*>(op)     = make_float4(rr[0], rr[1], rr[2], rr[3]);
        *reinterpret_cast<float4*>(op + 4) = make_float4(rr[4], rr[5], rr[6], rr[7]);
    }
}

extern "C" void kernel_launch(void* const* d_in, const int* in_sizes, int n_in,
                              void* d_out, int out_size, void* d_ws, size_t ws_size,
                              hipStream_t stream) {
    const float* x = (const float*)d_in[0];
    const float* k = (const float*)d_in[1];
    float* out = (float*)d_out;

    const int total = BB * HO * NXT;                 // 1,016,064 threads
    const int block = 256;
    const int grid  = total / block;                 // 3969 blocks, exact
    erosion2d_f16<<<grid, block, 0, stream>>>(x, k, out);
}